// Round 2
// baseline (9153.843 us; speedup 1.0000x reference)
//
#include <hip/hip_runtime.h>
#include <hip/hip_bf16.h>
#include <stdint.h>

// Problem constants
#define TT 256
#define BB 64
#define AA 512
#define II 1024
#define HH 1024
#define LL 2
// derived
#define BH 65536        // B*H
#define B4H 262144      // B*4H
#define OUT_HL 16777216
#define OUT_CL (16777216 + 131072)
#define NBLK 256

typedef __attribute__((ext_vector_type(8))) short bf16x8;
typedef __attribute__((ext_vector_type(4))) float f32x4;

__device__ __forceinline__ ushort f2bf(float v) {
    union { float f; uint32_t u; } x; x.f = v;
    uint32_t r = x.u + 0x7fff + ((x.u >> 16) & 1);
    return (ushort)(r >> 16);
}

// Build Wt[l][col'][k] bf16, col' = u*4+g for source column col=g*1024+u,
// k in [0,1024) from W_ih[k][col], k in [1024,2048) from W_hh[k-1024][col].
__global__ __launch_bounds__(256) void k_prep_wt(const float* __restrict__ wih,
                                                 const float* __restrict__ whh,
                                                 ushort* __restrict__ Wt) {
    __shared__ ushort tile[64][65];
    const int l = blockIdx.z;
    const int k0 = blockIdx.x * 64;    // 0..2047
    const int col0 = blockIdx.y * 64;  // 0..4095
    const int tid = threadIdx.x;
    const int cl = tid & 63, ks = tid >> 6;
    const float* src;
    int krow0;
    if (k0 < 1024) { src = wih + (size_t)l * 1024 * 4096; krow0 = k0; }
    else           { src = whh + (size_t)l * 1024 * 4096; krow0 = k0 - 1024; }
#pragma unroll
    for (int i = 0; i < 16; ++i) {
        int kl = ks + i * 4;
        tile[kl][cl] = f2bf(src[(size_t)(krow0 + kl) * 4096 + col0 + cl]);
    }
    __syncthreads();
    const int g0 = col0 >> 10, ub = col0 & 1023;
    ushort* dst = Wt + (size_t)l * 4096 * 2048;
    const int klane = tid & 63;
#pragma unroll
    for (int i = 0; i < 16; ++i) {
        int cl2 = (tid >> 6) + i * 4;
        int row = (ub + cl2) * 4 + g0;
        dst[(size_t)row * 2048 + k0 + klane] = tile[klane][cl2];
    }
}

__global__ __launch_bounds__(256) void k_cast_x(const float* __restrict__ x,
                                                ushort* __restrict__ xbf) {
    int i = blockIdx.x * 256 + threadIdx.x;
    const float4* xv = (const float4*)x;
    float4 v = xv[i];
    ushort4 o;
    o.x = f2bf(v.x); o.y = f2bf(v.y); o.z = f2bf(v.z); o.w = f2bf(v.w);
    ((ushort4*)xbf)[i] = o;
}

// const[l][b][col] = a0[b,:] @ W_ah[l][:,col] + bias_ah + bias_ih + bias_hh
__global__ __launch_bounds__(256) void k_const(const float* __restrict__ attn,
                                               const float* __restrict__ wah,
                                               const float* __restrict__ bah,
                                               const float* __restrict__ bih,
                                               const float* __restrict__ bhh,
                                               float* __restrict__ constg) {
    const int tid = threadIdx.x;
    const int col = blockIdx.x * 256 + tid;
    const int b0 = blockIdx.y * 8;
    const int l = blockIdx.z;
    const float* W = wah + (size_t)l * 512 * 4096;
    float acc[8] = {0.f, 0.f, 0.f, 0.f, 0.f, 0.f, 0.f, 0.f};
    for (int k = 0; k < 512; ++k) {
        float wv = W[(size_t)k * 4096 + col];
#pragma unroll
        for (int j = 0; j < 8; ++j) acc[j] += attn[(b0 + j) * 512 + k] * wv;
    }
    float bias = bah[l * 4096 + col] + bih[l * 4096 + col] + bhh[l * 4096 + col];
    float* cg = constg + (size_t)l * B4H;
#pragma unroll
    for (int j = 0; j < 8; ++j) cg[(size_t)(b0 + j) * 4096 + col] = acc[j] + bias;
}

__global__ __launch_bounds__(256) void k_init(const float* __restrict__ h0,
                                              ushort* __restrict__ hs0,
                                              ushort* __restrict__ h1,
                                              unsigned* __restrict__ bar) {
    int i = blockIdx.x * 256 + threadIdx.x; // 0..131071  ([L][B][H])
    float h = h0[i];
    if (i < BH) hs0[i] = f2bf(h);          // layer0 slot 0
    else        h1[i - BH] = f2bf(h);      // layer1 ping-pong slot 0
    if (i == 0) *bar = 0u;
}

// Persistent pipelined 2-layer LSTM. 256 blocks x 512 threads, 1 block/CU.
// Weights live in LDS for all 257 iterations; c-state and gate constants in
// registers. Iter s: layer0 (waves 0-3) computes t=s, layer1 (waves 4-7)
// computes t=s-1. One grid barrier per iteration.
__global__ __launch_bounds__(512, 1) void k_persist(
        const ushort* __restrict__ xbf,
        ushort* __restrict__ hs0,
        ushort* __restrict__ h1,
        const ushort* __restrict__ Wt,
        const float* __restrict__ constg,
        const float* __restrict__ c0,
        float* __restrict__ out,
        unsigned* __restrict__ bar) {
    // [2 layers][256 kgrp][16 col][8 k] bf16 = 128 KiB.
    // Wave read: slot = l*4096 + kt*64 + lane  -> contiguous 1KB, 0 conflicts.
    __shared__ ushort wlds[65536];
    __shared__ float gt[8][16][17];

    const int tid = threadIdx.x;
    const int w = tid >> 6, lane = tid & 63;
    const int layer = w >> 2, wm = w & 3;
    const int u0 = blockIdx.x * 4;

    // ---- stage weights into LDS (once) ----
#pragma unroll
    for (int i = 0; i < 16; ++i) {
        int c = i * 512 + tid;              // 0..8191 chunks of 16B
        int ly = c >> 12, r = c & 4095;
        int col = r >> 8, kg = r & 255;     // kgrp-major per col: coalesced src
        const ushort* src = Wt + ((size_t)(ly * 4096 + u0 * 4 + col)) * 2048 + kg * 8;
        bf16x8 v = *(const bf16x8*)src;
        int slot = ly * 4096 + kg * 16 + col;
        *(bf16x8*)(wlds + (size_t)slot * 8) = v;
    }

    // ---- per-thread launch-invariant state ----
    // MFMA C/D mapping: col = lane&15, row = (lane>>4)*4 + r
    const int cc = lane & 15;
    const int gu = u0 + (cc >> 2), gg_ = cc & 3, gcol = (gg_ << 10) + gu;
    const int r0 = (lane >> 4) * 4;
    const float* cgp = constg + (size_t)layer * B4H;
    float cg[4];
#pragma unroll
    for (int r = 0; r < 4; ++r)
        cg[r] = cgp[(size_t)(wm * 16 + r0 + r) * 4096 + gcol];

    // epilogue mapping: one (b,u) per lane per wave
    const int bl = lane & 15, ul = lane >> 4;
    const int eidx = (wm * 16 + bl) * 1024 + (u0 + ul);
    float creg = c0[layer * BH + eidx];

    const int bf_ = wm * 16 + (lane & 15);  // A-fragment batch row
    const int koff = (lane >> 4) * 8;       // A-fragment k offset
    const ushort* bbase = wlds + ((size_t)layer * 4096 + lane) * 8;

    __syncthreads();

    for (int s = 0; s <= TT; ++s) {
        int active, t;
        const ushort *Ax, *Ah;
        if (layer == 0) {
            active = (s < TT); t = s;
            Ax = xbf + (size_t)t * BH;
            Ah = hs0 + (size_t)s * BH;
        } else {
            active = (s >= 1); t = s - 1;
            Ax = hs0 + (size_t)s * BH;      // layer0 h_t, from previous iter
            Ah = h1 + (size_t)(t & 1) * BH;
        }

        if (active) {
            f32x4 acc = {0.f, 0.f, 0.f, 0.f};
            const ushort* Axl = Ax + (size_t)bf_ * 1024 + koff;
            const ushort* Ahl = Ah + (size_t)bf_ * 1024 + koff;
#pragma unroll 8
            for (int kt = 0; kt < 32; ++kt) {
                bf16x8 a = *(const bf16x8*)(Axl + kt * 32);
                bf16x8 b = *(const bf16x8*)(bbase + kt * 512);
                acc = __builtin_amdgcn_mfma_f32_16x16x32_bf16(a, b, acc, 0, 0, 0);
            }
#pragma unroll 8
            for (int kt = 0; kt < 32; ++kt) {
                bf16x8 a = *(const bf16x8*)(Ahl + kt * 32);
                bf16x8 b = *(const bf16x8*)(bbase + (32 + kt) * 512);
                acc = __builtin_amdgcn_mfma_f32_16x16x32_bf16(a, b, acc, 0, 0, 0);
            }
#pragma unroll
            for (int r = 0; r < 4; ++r)
                gt[w][r0 + r][cc] = acc[r] + cg[r];
        }
        __syncthreads();
        if (active) {
            float gi = gt[w][bl][ul * 4 + 0];
            float gf = gt[w][bl][ul * 4 + 1];
            float gv = gt[w][bl][ul * 4 + 2];
            float go = gt[w][bl][ul * 4 + 3];
            float si = 1.f / (1.f + __expf(-gi));
            float sf = 1.f / (1.f + __expf(-gf));
            float so = 1.f / (1.f + __expf(-go));
            float cn = sf * creg + si * tanhf(gv);
            float hv = so * tanhf(cn);
            creg = cn;
            ushort hb = f2bf(hv);
            if (layer == 0) {
                hs0[(size_t)(s + 1) * BH + eidx] = hb;
                if (s == TT - 1) {
                    out[OUT_HL + eidx] = hv;
                    out[OUT_CL + eidx] = cn;
                }
            } else {
                h1[(size_t)((t + 1) & 1) * BH + eidx] = hb;
                out[(size_t)t * BH + eidx] = hv;
                if (t == TT - 1) {
                    out[OUT_HL + BH + eidx] = hv;
                    out[OUT_CL + BH + eidx] = cn;
                }
            }
        }
        if (s < TT) {
            // grid barrier: monotonic counter, agent-scope fences
            __syncthreads();   // all waves' stores retired (vmcnt0 before barrier)
            if (tid == 0) {
                __threadfence();   // agent release: writeback L2
                __hip_atomic_fetch_add(bar, 1u, __ATOMIC_RELAXED, __HIP_MEMORY_SCOPE_AGENT);
                unsigned target = (unsigned)NBLK * (unsigned)(s + 1);
                while (__hip_atomic_load(bar, __ATOMIC_RELAXED, __HIP_MEMORY_SCOPE_AGENT) < target)
                    __builtin_amdgcn_s_sleep(1);
                __threadfence();   // agent acquire: invalidate L1/L2
            }
            __syncthreads();
        }
    }
}

extern "C" void kernel_launch(void* const* d_in, const int* in_sizes, int n_in,
                              void* d_out, int out_size, void* d_ws, size_t ws_size,
                              hipStream_t stream) {
    const float* attn = (const float*)d_in[0];
    const float* x    = (const float*)d_in[1];
    const float* h0   = (const float*)d_in[3];
    const float* c0   = (const float*)d_in[4];
    const float* wah  = (const float*)d_in[5];
    const float* wih  = (const float*)d_in[6];
    const float* whh  = (const float*)d_in[7];
    const float* bah  = (const float*)d_in[8];
    const float* bih  = (const float*)d_in[9];
    const float* bhh  = (const float*)d_in[10];
    float* out = (float*)d_out;

    char* ws = (char*)d_ws;
    ushort*   Wt     = (ushort*)(ws);              // [2][4096][2048] bf16 : 33,554,432
    ushort*   xbf    = (ushort*)(ws + 33554432);   // [256][64][1024] bf16 : 33,554,432
    ushort*   hs0    = (ushort*)(ws + 67108864);   // [257][64][1024] bf16 : 33,685,504
    ushort*   h1     = (ushort*)(ws + 100794368);  // [2][64][1024]  bf16 : 262,144
    float*    constg = (float*)(ws + 101056512);   // [2][64][4096]  f32  : 2,097,152
    unsigned* bar    = (unsigned*)(ws + 103153664);

    hipLaunchKernelGGL(k_prep_wt, dim3(32, 64, 2), dim3(256), 0, stream, wih, whh, Wt);
    hipLaunchKernelGGL(k_cast_x, dim3(16384), dim3(256), 0, stream, x, xbf);
    hipLaunchKernelGGL(k_const, dim3(16, 8, 2), dim3(256), 0, stream, attn, wah, bah, bih, bhh, constg);
    hipLaunchKernelGGL(k_init, dim3(512), dim3(256), 0, stream, h0, hs0, h1, bar);

    void* args[] = { (void*)&xbf, (void*)&hs0, (void*)&h1, (void*)&Wt,
                     (void*)&constg, (void*)&c0, (void*)&out, (void*)&bar };
    hipLaunchCooperativeKernel((void*)k_persist, dim3(NBLK), dim3(512), args, 0, stream);
}

// Round 3
// 5125.351 us; speedup vs baseline: 1.7860x; 1.7860x over previous
//
#include <hip/hip_runtime.h>
#include <hip/hip_bf16.h>
#include <stdint.h>

// Problem constants
#define TT 256
#define BB 64
#define AA 512
#define II 1024
#define HH 1024
#define LL 2
// derived
#define BH 65536        // B*H
#define B4H 262144      // B*4H
#define OUT_HL 16777216
#define OUT_CL (16777216 + 131072)
#define NBLK 256

typedef __attribute__((ext_vector_type(8))) short bf16x8;
typedef __attribute__((ext_vector_type(4))) float f32x4;
typedef __attribute__((ext_vector_type(4))) unsigned int u32x4;

__device__ __forceinline__ ushort f2bf(float v) {
    union { float f; uint32_t u; } x; x.f = v;
    uint32_t r = x.u + 0x7fff + ((x.u >> 16) & 1);
    return (ushort)(r >> 16);
}

// Build Wt[l][col'][k] bf16, col' = u*4+g for source column col=g*1024+u,
// k in [0,1024) from W_ih[k][col], k in [1024,2048) from W_hh[k-1024][col].
__global__ __launch_bounds__(256) void k_prep_wt(const float* __restrict__ wih,
                                                 const float* __restrict__ whh,
                                                 ushort* __restrict__ Wt) {
    __shared__ ushort tile[64][65];
    const int l = blockIdx.z;
    const int k0 = blockIdx.x * 64;    // 0..2047
    const int col0 = blockIdx.y * 64;  // 0..4095
    const int tid = threadIdx.x;
    const int cl = tid & 63, ks = tid >> 6;
    const float* src;
    int krow0;
    if (k0 < 1024) { src = wih + (size_t)l * 1024 * 4096; krow0 = k0; }
    else           { src = whh + (size_t)l * 1024 * 4096; krow0 = k0 - 1024; }
#pragma unroll
    for (int i = 0; i < 16; ++i) {
        int kl = ks + i * 4;
        tile[kl][cl] = f2bf(src[(size_t)(krow0 + kl) * 4096 + col0 + cl]);
    }
    __syncthreads();
    const int g0 = col0 >> 10, ub = col0 & 1023;
    ushort* dst = Wt + (size_t)l * 4096 * 2048;
    const int klane = tid & 63;
#pragma unroll
    for (int i = 0; i < 16; ++i) {
        int cl2 = (tid >> 6) + i * 4;
        int row = (ub + cl2) * 4 + g0;
        dst[(size_t)row * 2048 + k0 + klane] = tile[klane][cl2];
    }
}

__global__ __launch_bounds__(256) void k_cast_x(const float* __restrict__ x,
                                                ushort* __restrict__ xbf) {
    int i = blockIdx.x * 256 + threadIdx.x;
    const float4* xv = (const float4*)x;
    float4 v = xv[i];
    ushort4 o;
    o.x = f2bf(v.x); o.y = f2bf(v.y); o.z = f2bf(v.z); o.w = f2bf(v.w);
    ((ushort4*)xbf)[i] = o;
}

// const[l][b][col] = a0[b,:] @ W_ah[l][:,col] + bias_ah + bias_ih + bias_hh
__global__ __launch_bounds__(256) void k_const(const float* __restrict__ attn,
                                               const float* __restrict__ wah,
                                               const float* __restrict__ bah,
                                               const float* __restrict__ bih,
                                               const float* __restrict__ bhh,
                                               float* __restrict__ constg) {
    const int tid = threadIdx.x;
    const int col = blockIdx.x * 256 + tid;
    const int b0 = blockIdx.y * 8;
    const int l = blockIdx.z;
    const float* W = wah + (size_t)l * 512 * 4096;
    float acc[8] = {0.f, 0.f, 0.f, 0.f, 0.f, 0.f, 0.f, 0.f};
    for (int k = 0; k < 512; ++k) {
        float wv = W[(size_t)k * 4096 + col];
#pragma unroll
        for (int j = 0; j < 8; ++j) acc[j] += attn[(b0 + j) * 512 + k] * wv;
    }
    float bias = bah[l * 4096 + col] + bih[l * 4096 + col] + bhh[l * 4096 + col];
    float* cg = constg + (size_t)l * B4H;
#pragma unroll
    for (int j = 0; j < 8; ++j) cg[(size_t)(b0 + j) * 4096 + col] = acc[j] + bias;
}

__global__ __launch_bounds__(256) void k_init(const float* __restrict__ h0,
                                              ushort* __restrict__ hs0,
                                              ushort* __restrict__ h1,
                                              unsigned* __restrict__ flags) {
    int i = blockIdx.x * 256 + threadIdx.x; // 0..131071  ([L][B][H])
    float h = h0[i];
    if (i < BH) hs0[i] = f2bf(h);          // layer0 slot 0
    else        h1[i - BH] = f2bf(h);      // layer1 ping-pong slot 0
    if (i < NBLK) flags[i] = 0u;
}

// ---- inline-asm helpers ----
// Issue one chunk of 8 x 16B A-fragment loads. SC: device-coherent (bypass L1/L2).
#define ISSUE(BUF, BASE, SC)                                                   \
    do {                                                                       \
        if (SC) {                                                              \
            _Pragma("unroll")                                                  \
            for (int _i = 0; _i < 8; ++_i)                                     \
                asm volatile("global_load_dwordx4 %0, %1, off sc0 sc1"         \
                             : "=v"(BUF[_i]) : "v"((BASE) + _i * 32));         \
        } else {                                                               \
            _Pragma("unroll")                                                  \
            for (int _i = 0; _i < 8; ++_i)                                     \
                asm volatile("global_load_dwordx4 %0, %1, off"                 \
                             : "=v"(BUF[_i]) : "v"((BASE) + _i * 32));         \
        }                                                                      \
    } while (0)

// Wait until chunk's loads landed (N = allowed outstanding), then 8 MFMAs.
#define CONSUME(BUF, c, N)                                                     \
    do {                                                                       \
        asm volatile("s_waitcnt vmcnt(" #N ")" ::: "memory");                  \
        __builtin_amdgcn_sched_barrier(0x100); /* only DS_READ may cross */    \
        _Pragma("unroll")                                                      \
        for (int _i = 0; _i < 8; ++_i) {                                       \
            bf16x8 b = *(const bf16x8*)(bbase + ((c) * 8 + _i) * 512);         \
            acc = __builtin_amdgcn_mfma_f32_16x16x32_bf16(BUF[_i], b, acc, 0, 0, 0); \
        }                                                                      \
    } while (0)

// Persistent pipelined 2-layer LSTM. 256 blocks x 512 threads, 1 block/CU.
// Weights in LDS; c-state + gate constants in registers. Iter s: layer0
// (waves 0-3) computes t=s, layer1 (waves 4-7) computes t=s-1. One flag-array
// grid barrier per iteration; h exchanged via write-through (sc0 sc1) stores.
__global__ __launch_bounds__(512, 1) void k_persist(
        const ushort* __restrict__ xbf,
        ushort* __restrict__ hs0,
        ushort* __restrict__ h1,
        const ushort* __restrict__ Wt,
        const float* __restrict__ constg,
        const float* __restrict__ c0,
        float* __restrict__ out,
        unsigned* __restrict__ flags) {
    // [2 layers][256 kgrp][16 col][8 k] bf16 = 128 KiB.
    __shared__ ushort wlds[65536];
    __shared__ float gt[8][16][17];

    const int tid = threadIdx.x;
    const int w = tid >> 6, lane = tid & 63;
    const int layer = w >> 2, wm = w & 3;
    const int u0 = blockIdx.x * 4;
    const int bid = blockIdx.x;

    // ---- stage weights into LDS (once) ----
#pragma unroll
    for (int i = 0; i < 16; ++i) {
        int c = i * 512 + tid;              // 0..8191 chunks of 16B
        int ly = c >> 12, r = c & 4095;
        int col = r >> 8, kg = r & 255;
        const ushort* src = Wt + ((size_t)(ly * 4096 + u0 * 4 + col)) * 2048 + kg * 8;
        bf16x8 v = *(const bf16x8*)src;
        int slot = ly * 4096 + kg * 16 + col;
        *(bf16x8*)(wlds + (size_t)slot * 8) = v;
    }

    // ---- per-thread launch-invariant state ----
    // MFMA C/D mapping: col = lane&15, row = (lane>>4)*4 + r
    const int cc = lane & 15;
    const int gu = u0 + (cc >> 2), gg_ = cc & 3, gcol = (gg_ << 10) + gu;
    const int r0 = (lane >> 4) * 4;
    const float* cgp = constg + (size_t)layer * B4H;
    float cg[4];
#pragma unroll
    for (int r = 0; r < 4; ++r)
        cg[r] = cgp[(size_t)(wm * 16 + r0 + r) * 4096 + gcol];

    const int bl = lane & 15, ul = lane >> 4;
    const int eidx = (wm * 16 + bl) * 1024 + (u0 + ul);
    float creg = c0[layer * BH + eidx];

    const int bf_ = wm * 16 + (lane & 15);  // A-fragment batch row
    const int koff = (lane >> 4) * 8;       // A-fragment k offset
    const ushort* bbase = wlds + ((size_t)layer * 4096 + lane) * 8;

    __syncthreads();

    for (int s = 0; s <= TT; ++s) {
        int active, t;
        const ushort *Ax, *Ah;
        if (layer == 0) {
            active = (s < TT); t = s;
            Ax = xbf + (size_t)t * BH;      // ancient, L2-cacheable
            Ah = hs0 + (size_t)s * BH;      // fresh ADDRESS each iter -> plain ok
        } else {
            active = (s >= 1); t = s - 1;
            Ax = hs0 + (size_t)s * BH;      // fresh address -> plain ok
            Ah = h1 + (size_t)(t & 1) * BH; // REUSED address -> must bypass (sc)
        }
        const int sc_ah = (layer == 1);

        if (active) {
            f32x4 acc = {0.f, 0.f, 0.f, 0.f};
            const ushort* Axl = Ax + (size_t)bf_ * 1024 + koff;
            const ushort* Ahl = Ah + (size_t)bf_ * 1024 + koff;
            bf16x8 bufA[8], bufB[8], bufC[8], bufD[8];
            // chunks 0-3: Ax half (k 0..1023); chunks 4-7: Ah half.
            ISSUE(bufA, Axl + 0 * 256, 0);
            ISSUE(bufB, Axl + 1 * 256, 0);
            ISSUE(bufC, Axl + 2 * 256, 0);
            ISSUE(bufD, Axl + 3 * 256, 0);
            CONSUME(bufA, 0, 24); ISSUE(bufA, Ahl + 0 * 256, sc_ah);
            CONSUME(bufB, 1, 24); ISSUE(bufB, Ahl + 1 * 256, sc_ah);
            CONSUME(bufC, 2, 24); ISSUE(bufC, Ahl + 2 * 256, sc_ah);
            CONSUME(bufD, 3, 24); ISSUE(bufD, Ahl + 3 * 256, sc_ah);
            CONSUME(bufA, 4, 24);
            CONSUME(bufB, 5, 16);
            CONSUME(bufC, 6, 8);
            CONSUME(bufD, 7, 0);
#pragma unroll
            for (int r = 0; r < 4; ++r)
                gt[w][r0 + r][cc] = acc[r] + cg[r];
        }
        __syncthreads();
        if (active) {
            float gi = gt[w][bl][ul * 4 + 0];
            float gf = gt[w][bl][ul * 4 + 1];
            float gv = gt[w][bl][ul * 4 + 2];
            float go = gt[w][bl][ul * 4 + 3];
            float si = 1.f / (1.f + __expf(-gi));
            float sf = 1.f / (1.f + __expf(-gf));
            float so = 1.f / (1.f + __expf(-go));
            float cn = sf * creg + si * tanhf(gv);
            float hv = so * tanhf(cn);
            creg = cn;
            uint32_t hb = (uint32_t)f2bf(hv);
            if (layer == 0) {
                ushort* hp = hs0 + (size_t)(s + 1) * BH + eidx;
                asm volatile("global_store_short %0, %1, off sc0 sc1"
                             :: "v"(hp), "v"(hb) : "memory");
                if (s == TT - 1) {
                    out[OUT_HL + eidx] = hv;
                    out[OUT_CL + eidx] = cn;
                }
            } else {
                ushort* hp = h1 + (size_t)((t + 1) & 1) * BH + eidx;
                asm volatile("global_store_short %0, %1, off sc0 sc1"
                             :: "v"(hp), "v"(hb) : "memory");
                out[(size_t)t * BH + eidx] = hv;
                if (t == TT - 1) {
                    out[OUT_HL + BH + eidx] = hv;
                    out[OUT_CL + BH + eidx] = cn;
                }
            }
        }
        if (s < TT) {
            // drain ALL this wave's stores (asm stores are invisible to the
            // compiler's counting), then block-barrier: all waves drained.
            asm volatile("s_waitcnt vmcnt(0)" ::: "memory");
            __syncthreads();
            unsigned target = (unsigned)(s + 1);
            if (tid == 0) {
                unsigned* fp = flags + bid;
                asm volatile("global_store_dword %0, %1, off sc0 sc1"
                             :: "v"(fp), "v"(target) : "memory");
            }
            if (w == 0) {
                const unsigned* fp = flags + lane * 4;
                while (true) {
                    u32x4 f;
                    asm volatile("global_load_dwordx4 %0, %1, off sc0 sc1\n\t"
                                 "s_waitcnt vmcnt(0)"
                                 : "=v"(f) : "v"(fp) : "memory");
                    int ok = (f.x >= target) && (f.y >= target) &&
                             (f.z >= target) && (f.w >= target);
                    if (__all(ok)) break;
                    __builtin_amdgcn_s_sleep(2);
                }
            }
            __syncthreads();
        }
    }
}

extern "C" void kernel_launch(void* const* d_in, const int* in_sizes, int n_in,
                              void* d_out, int out_size, void* d_ws, size_t ws_size,
                              hipStream_t stream) {
    const float* attn = (const float*)d_in[0];
    const float* x    = (const float*)d_in[1];
    const float* h0   = (const float*)d_in[3];
    const float* c0   = (const float*)d_in[4];
    const float* wah  = (const float*)d_in[5];
    const float* wih  = (const float*)d_in[6];
    const float* whh  = (const float*)d_in[7];
    const float* bah  = (const float*)d_in[8];
    const float* bih  = (const float*)d_in[9];
    const float* bhh  = (const float*)d_in[10];
    float* out = (float*)d_out;

    char* ws = (char*)d_ws;
    ushort*   Wt     = (ushort*)(ws);              // [2][4096][2048] bf16 : 33,554,432
    ushort*   xbf    = (ushort*)(ws + 33554432);   // [256][64][1024] bf16 : 33,554,432
    ushort*   hs0    = (ushort*)(ws + 67108864);   // [257][64][1024] bf16 : 33,685,504
    ushort*   h1     = (ushort*)(ws + 100794368);  // [2][64][1024]  bf16 : 262,144
    float*    constg = (float*)(ws + 101056512);   // [2][64][4096]  f32  : 2,097,152
    unsigned* flags  = (unsigned*)(ws + 103153664);// [256] u32

    hipLaunchKernelGGL(k_prep_wt, dim3(32, 64, 2), dim3(256), 0, stream, wih, whh, Wt);
    hipLaunchKernelGGL(k_cast_x, dim3(16384), dim3(256), 0, stream, x, xbf);
    hipLaunchKernelGGL(k_const, dim3(16, 8, 2), dim3(256), 0, stream, attn, wah, bah, bih, bhh, constg);
    hipLaunchKernelGGL(k_init, dim3(512), dim3(256), 0, stream, h0, hs0, h1, flags);

    void* args[] = { (void*)&xbf, (void*)&hs0, (void*)&h1, (void*)&Wt,
                     (void*)&constg, (void*)&c0, (void*)&out, (void*)&flags };
    hipLaunchCooperativeKernel((void*)k_persist, dim3(NBLK), dim3(512), args, 0, stream);
}

// Round 4
// 2621.545 us; speedup vs baseline: 3.4918x; 1.9551x over previous
//
#include <hip/hip_runtime.h>
#include <hip/hip_bf16.h>
#include <stdint.h>

// Problem constants
#define TT 256
#define BB 64
#define AA 512
#define II 1024
#define HH 1024
#define LL 2
// derived
#define BH 65536        // B*H
#define B4H 262144      // B*4H
#define OUT_HL 16777216
#define OUT_CL (16777216 + 131072)
#define NBLK 256

typedef __attribute__((ext_vector_type(8))) short bf16x8;
typedef __attribute__((ext_vector_type(4))) float f32x4;
typedef __attribute__((ext_vector_type(4))) unsigned int u32x4;
typedef __attribute__((ext_vector_type(2))) unsigned int u32x2;

__device__ __forceinline__ ushort f2bf(float v) {
    union { float f; uint32_t u; } x; x.f = v;
    uint32_t r = x.u + 0x7fff + ((x.u >> 16) & 1);
    return (ushort)(r >> 16);
}

// Fragment-major layout for [64][1024] bf16 activation slabs:
//   off(b,u) = (b>>4)*16384 + (u>>5)*512 + ((u>>3)&3)*128 + (b&15)*8 + (u&7)
// A wave loading m-tile r, k-tile kt reads 64 lanes x 16B CONTIGUOUS 1KB.

// Build Wt[l][col'][k] bf16, col' = u*4+g for source column col=g*1024+u.
__global__ __launch_bounds__(256) void k_prep_wt(const float* __restrict__ wih,
                                                 const float* __restrict__ whh,
                                                 ushort* __restrict__ Wt) {
    __shared__ ushort tile[64][65];
    const int l = blockIdx.z;
    const int k0 = blockIdx.x * 64;    // 0..2047
    const int col0 = blockIdx.y * 64;  // 0..4095
    const int tid = threadIdx.x;
    const int cl = tid & 63, ks = tid >> 6;
    const float* src;
    int krow0;
    if (k0 < 1024) { src = wih + (size_t)l * 1024 * 4096; krow0 = k0; }
    else           { src = whh + (size_t)l * 1024 * 4096; krow0 = k0 - 1024; }
#pragma unroll
    for (int i = 0; i < 16; ++i) {
        int kl = ks + i * 4;
        tile[kl][cl] = f2bf(src[(size_t)(krow0 + kl) * 4096 + col0 + cl]);
    }
    __syncthreads();
    const int g0 = col0 >> 10, ub = col0 & 1023;
    ushort* dst = Wt + (size_t)l * 4096 * 2048;
    const int klane = tid & 63;
#pragma unroll
    for (int i = 0; i < 16; ++i) {
        int cl2 = (tid >> 6) + i * 4;
        int row = (ub + cl2) * 4 + g0;
        dst[(size_t)row * 2048 + k0 + klane] = tile[klane][cl2];
    }
}

// x -> bf16 fragment-major xbfF[t][...]
__global__ __launch_bounds__(256) void k_cast_x(const float* __restrict__ x,
                                                ushort* __restrict__ xbfF) {
    int i = blockIdx.x * 256 + threadIdx.x;   // [256 t][64 b][128 k8]
    int k8 = i & 127, b = (i >> 7) & 63, t = i >> 13;
    const float4* xs = (const float4*)(x + (((size_t)t * 64 + b) * 1024 + k8 * 8));
    float4 a = xs[0], c = xs[1];
    uint4 pk;
    pk.x = (uint)f2bf(a.x) | ((uint)f2bf(a.y) << 16);
    pk.y = (uint)f2bf(a.z) | ((uint)f2bf(a.w) << 16);
    pk.z = (uint)f2bf(c.x) | ((uint)f2bf(c.y) << 16);
    pk.w = (uint)f2bf(c.z) | ((uint)f2bf(c.w) << 16);
    size_t off = (size_t)t * 65536 + (size_t)(b >> 4) * 16384 +
                 (size_t)(k8 >> 2) * 512 + (size_t)(k8 & 3) * 128 + (size_t)(b & 15) * 8;
    *(uint4*)(xbfF + off) = pk;
}

// const[l][b][col] = a0[b,:] @ W_ah[l][:,col] + bias_ah + bias_ih + bias_hh
__global__ __launch_bounds__(256) void k_const(const float* __restrict__ attn,
                                               const float* __restrict__ wah,
                                               const float* __restrict__ bah,
                                               const float* __restrict__ bih,
                                               const float* __restrict__ bhh,
                                               float* __restrict__ constg) {
    const int tid = threadIdx.x;
    const int col = blockIdx.x * 256 + tid;
    const int b0 = blockIdx.y * 8;
    const int l = blockIdx.z;
    const float* W = wah + (size_t)l * 512 * 4096;
    float acc[8] = {0.f, 0.f, 0.f, 0.f, 0.f, 0.f, 0.f, 0.f};
    for (int k = 0; k < 512; ++k) {
        float wv = W[(size_t)k * 4096 + col];
#pragma unroll
        for (int j = 0; j < 8; ++j) acc[j] += attn[(b0 + j) * 512 + k] * wv;
    }
    float bias = bah[l * 4096 + col] + bih[l * 4096 + col] + bhh[l * 4096 + col];
    float* cg = constg + (size_t)l * B4H;
#pragma unroll
    for (int j = 0; j < 8; ++j) cg[(size_t)(b0 + j) * 4096 + col] = acc[j] + bias;
}

// h0 -> fragment-major initial slots
__global__ __launch_bounds__(256) void k_init(const float* __restrict__ h0,
                                              ushort* __restrict__ hs0F,
                                              ushort* __restrict__ h1F,
                                              unsigned* __restrict__ flags) {
    int i = blockIdx.x * 256 + threadIdx.x;   // [2 l][64 b][128 k8] = 16384
    if (i < 16384) {
        int k8 = i & 127, b = (i >> 7) & 63, l = i >> 13;
        const float* src = h0 + ((size_t)(l * 64 + b) * 1024 + k8 * 8);
        uint4 pk;
        pk.x = (uint)f2bf(src[0]) | ((uint)f2bf(src[1]) << 16);
        pk.y = (uint)f2bf(src[2]) | ((uint)f2bf(src[3]) << 16);
        pk.z = (uint)f2bf(src[4]) | ((uint)f2bf(src[5]) << 16);
        pk.w = (uint)f2bf(src[6]) | ((uint)f2bf(src[7]) << 16);
        size_t off = (size_t)(b >> 4) * 16384 + (size_t)(k8 >> 2) * 512 +
                     (size_t)(k8 & 3) * 128 + (size_t)(b & 15) * 8;
        *(uint4*)((l == 0 ? hs0F : h1F) + off) = pk;
    }
    if (i < NBLK) flags[i] = 0u;
}

// ---- inline-asm helpers ----
// Issue one chunk of 8 x 16B fragment loads (contiguous 1KB per instr).
#define ISSUE(BUF, BASE, SC)                                                   \
    do {                                                                       \
        if (SC) {                                                              \
            _Pragma("unroll")                                                  \
            for (int _i = 0; _i < 8; ++_i)                                     \
                asm volatile("global_load_dwordx4 %0, %1, off sc0 sc1"         \
                             : "=v"(BUF[_i]) : "v"((BASE) + _i * 512));        \
        } else {                                                               \
            _Pragma("unroll")                                                  \
            for (int _i = 0; _i < 8; ++_i)                                     \
                asm volatile("global_load_dwordx4 %0, %1, off"                 \
                             : "=v"(BUF[_i]) : "v"((BASE) + _i * 512));        \
        }                                                                      \
    } while (0)

#define CONSUME(BUF, c, N)                                                     \
    do {                                                                       \
        asm volatile("s_waitcnt vmcnt(" #N ")" ::: "memory");                  \
        __builtin_amdgcn_sched_barrier(0x100);                                 \
        _Pragma("unroll")                                                      \
        for (int _i = 0; _i < 8; ++_i) {                                       \
            bf16x8 b = *(const bf16x8*)(bbase + ((c) * 8 + _i) * 512);         \
            acc = __builtin_amdgcn_mfma_f32_16x16x32_bf16(BUF[_i], b, acc, 0, 0, 0); \
        }                                                                      \
    } while (0)

// Persistent pipelined 2-layer LSTM. 256 blocks x 512 threads, 1 block/CU.
__global__ __launch_bounds__(512, 1) void k_persist(
        const ushort* __restrict__ xbfF,
        ushort* __restrict__ hs0F,
        ushort* __restrict__ h1F,
        const ushort* __restrict__ Wt,
        const float* __restrict__ constg,
        const float* __restrict__ c0,
        float* __restrict__ out,
        unsigned* __restrict__ flags) {
    __shared__ ushort wlds[65536];   // [2 l][256 kg][16 col][8 k] = 128 KiB
    __shared__ float gt[8][16][17];

    const int tid = threadIdx.x;
    const int w = tid >> 6, lane = tid & 63;
    const int layer = w >> 2, wm = w & 3;
    const int u0 = blockIdx.x * 4;
    const int bid = blockIdx.x;

    // ---- stage weights into LDS (once) ----
#pragma unroll
    for (int i = 0; i < 16; ++i) {
        int c = i * 512 + tid;
        int ly = c >> 12, r = c & 4095;
        int col = r >> 8, kg = r & 255;
        const ushort* src = Wt + ((size_t)(ly * 4096 + u0 * 4 + col)) * 2048 + kg * 8;
        bf16x8 v = *(const bf16x8*)src;
        int slot = ly * 4096 + kg * 16 + col;
        *(bf16x8*)(wlds + (size_t)slot * 8) = v;
    }

    // ---- launch-invariant per-thread state ----
    // MFMA C/D mapping: col = lane&15, row = (lane>>4)*4 + r
    const int cc = lane & 15;
    const int gu = u0 + (cc >> 2), gg_ = cc & 3, gcol = (gg_ << 10) + gu;
    const int r0 = (lane >> 4) * 4;
    const float* cgp = constg + (size_t)layer * B4H;
    float cg[4];
#pragma unroll
    for (int r = 0; r < 4; ++r)
        cg[r] = cgp[(size_t)(wm * 16 + r0 + r) * 4096 + gcol];

    const int bl = lane & 15, ul = lane >> 4;
    const int eidx = (wm * 16 + bl) * 1024 + (u0 + ul);
    float creg = c0[layer * BH + eidx];

    // fragment-major read base offset for this lane (ushorts)
    const size_t fro = (size_t)wm * 16384 + (size_t)lane * 8;
    // packed h-store offset (ushorts), lanes 0-15 store dwordx2
    const int hoff = wm * 16384 + ((u0 >> 5) << 9) + (((u0 >> 3) & 3) << 7) +
                     (bl << 3) + (u0 & 4);
    const ushort* bbase = wlds + ((size_t)layer * 4096 + lane) * 8;

    __syncthreads();

    for (int s = 0; s <= TT; ++s) {
        int active, t;
        const ushort *Axl, *Ahl;
        int sc_ah;
        if (layer == 0) {
            active = (s < TT); t = s;
            Axl = xbfF + (size_t)t * 65536 + fro;   // static input
            Ahl = hs0F + (size_t)s * 65536 + fro;   // fresh address each iter
            sc_ah = 0;
        } else {
            active = (s >= 1); t = s - 1;
            Axl = hs0F + (size_t)s * 65536 + fro;   // fresh address
            Ahl = h1F + (size_t)(t & 1) * 65536 + fro; // reused addr -> bypass
            sc_ah = 1;
        }

        if (active) {
            f32x4 acc = {0.f, 0.f, 0.f, 0.f};
            bf16x8 bufA[8], bufB[8], bufC[8], bufD[8];
            ISSUE(bufA, Axl + 0 * 4096, 0);
            ISSUE(bufB, Axl + 1 * 4096, 0);
            ISSUE(bufC, Axl + 2 * 4096, 0);
            ISSUE(bufD, Axl + 3 * 4096, 0);
            CONSUME(bufA, 0, 24); ISSUE(bufA, Ahl + 0 * 4096, sc_ah);
            CONSUME(bufB, 1, 24); ISSUE(bufB, Ahl + 1 * 4096, sc_ah);
            CONSUME(bufC, 2, 24); ISSUE(bufC, Ahl + 2 * 4096, sc_ah);
            CONSUME(bufD, 3, 24); ISSUE(bufD, Ahl + 3 * 4096, sc_ah);
            CONSUME(bufA, 4, 24);
            CONSUME(bufB, 5, 16);
            CONSUME(bufC, 6, 8);
            CONSUME(bufD, 7, 0);
#pragma unroll
            for (int r = 0; r < 4; ++r)
                gt[w][r0 + r][cc] = acc[r] + cg[r];
            // gt is wave-private: wave-local ordering is enough (DS in-order per wave)
            __builtin_amdgcn_wave_barrier();
            asm volatile("s_waitcnt lgkmcnt(0)" ::: "memory");
            float gi = gt[w][bl][ul * 4 + 0];
            float gf = gt[w][bl][ul * 4 + 1];
            float gv = gt[w][bl][ul * 4 + 2];
            float go = gt[w][bl][ul * 4 + 3];
            float si = 1.f / (1.f + __expf(-gi));
            float sf = 1.f / (1.f + __expf(-gf));
            float so = 1.f / (1.f + __expf(-go));
            float cn = sf * creg + si * tanhf(gv);
            float hv = so * tanhf(cn);
            creg = cn;
            uint hb = (uint)f2bf(hv);
            // pack 4 u-values per batch row via intra-wave shuffles
            uint g0 = __shfl(hb, bl);
            uint g1 = __shfl(hb, bl + 16);
            uint g2 = __shfl(hb, bl + 32);
            uint g3 = __shfl(hb, bl + 48);
            u32x2 hp;
            hp.x = (g0 & 0xffffu) | (g1 << 16);
            hp.y = (g2 & 0xffffu) | (g3 << 16);
            ushort* hdst = (layer == 0 ? hs0F + (size_t)(s + 1) * 65536
                                       : h1F + (size_t)((t + 1) & 1) * 65536) + hoff;
            if (lane < 16)
                asm volatile("global_store_dwordx2 %0, %1, off sc0 sc1"
                             :: "v"(hdst), "v"(hp) : "memory");
            if (layer == 1) {
                float4 ov;
                ov.x = __shfl(hv, bl);
                ov.y = __shfl(hv, bl + 16);
                ov.z = __shfl(hv, bl + 32);
                ov.w = __shfl(hv, bl + 48);
                if (lane < 16)
                    *(float4*)(out + (size_t)t * 65536 + (wm * 16 + bl) * 1024 + u0) = ov;
                if (t == TT - 1) {
                    out[OUT_HL + BH + eidx] = hv;
                    out[OUT_CL + BH + eidx] = cn;
                }
            } else if (s == TT - 1) {
                out[OUT_HL + eidx] = hv;
                out[OUT_CL + eidx] = cn;
            }
        }
        if (s < TT) {
            asm volatile("s_waitcnt vmcnt(0)" ::: "memory");
            __syncthreads();
            unsigned target = (unsigned)(s + 1);
            if (tid == 0) {
                unsigned* fp = flags + bid;
                asm volatile("global_store_dword %0, %1, off sc0 sc1"
                             :: "v"(fp), "v"(target) : "memory");
            }
            if (w == 0) {
                const unsigned* fp = flags + lane * 4;
                while (true) {
                    u32x4 f;
                    asm volatile("global_load_dwordx4 %0, %1, off sc0 sc1\n\t"
                                 "s_waitcnt vmcnt(0)"
                                 : "=v"(f) : "v"(fp) : "memory");
                    int ok = (f.x >= target) && (f.y >= target) &&
                             (f.z >= target) && (f.w >= target);
                    if (__all(ok)) break;
                    __builtin_amdgcn_s_sleep(8);
                }
            }
            __syncthreads();
        }
    }
}

extern "C" void kernel_launch(void* const* d_in, const int* in_sizes, int n_in,
                              void* d_out, int out_size, void* d_ws, size_t ws_size,
                              hipStream_t stream) {
    const float* attn = (const float*)d_in[0];
    const float* x    = (const float*)d_in[1];
    const float* h0   = (const float*)d_in[3];
    const float* c0   = (const float*)d_in[4];
    const float* wah  = (const float*)d_in[5];
    const float* wih  = (const float*)d_in[6];
    const float* whh  = (const float*)d_in[7];
    const float* bah  = (const float*)d_in[8];
    const float* bih  = (const float*)d_in[9];
    const float* bhh  = (const float*)d_in[10];
    float* out = (float*)d_out;

    char* ws = (char*)d_ws;
    ushort*   Wt     = (ushort*)(ws);              // [2][4096][2048] bf16 : 33,554,432
    ushort*   xbfF   = (ushort*)(ws + 33554432);   // frag-major x     : 33,554,432
    ushort*   hs0F   = (ushort*)(ws + 67108864);   // [257] slots      : 33,685,504
    ushort*   h1F    = (ushort*)(ws + 100794368);  // [2] slots        : 262,144
    float*    constg = (float*)(ws + 101056512);   // [2][64][4096]    : 2,097,152
    unsigned* flags  = (unsigned*)(ws + 103153664);// [256] u32

    hipLaunchKernelGGL(k_prep_wt, dim3(32, 64, 2), dim3(256), 0, stream, wih, whh, Wt);
    hipLaunchKernelGGL(k_cast_x, dim3(8192), dim3(256), 0, stream, x, xbfF);
    hipLaunchKernelGGL(k_const, dim3(16, 8, 2), dim3(256), 0, stream, attn, wah, bah, bih, bhh, constg);
    hipLaunchKernelGGL(k_init, dim3(64), dim3(256), 0, stream, h0, hs0F, h1F, flags);

    void* args[] = { (void*)&xbfF, (void*)&hs0F, (void*)&h1F, (void*)&Wt,
                     (void*)&constg, (void*)&c0, (void*)&out, (void*)&flags };
    hipLaunchCooperativeKernel((void*)k_persist, dim3(NBLK), dim3(512), args, 0, stream);
}

// Round 6
// 1721.248 us; speedup vs baseline: 5.3181x; 1.5230x over previous
//
#include <hip/hip_runtime.h>
#include <hip/hip_bf16.h>
#include <stdint.h>

// Problem constants
#define TT 256
#define BB 64
#define AA 512
#define II 1024
#define HH 1024
#define LL 2
// derived
#define BH 65536        // B*H
#define B4H 262144      // B*4H
#define OUT_HL 16777216
#define OUT_CL (16777216 + 131072)
#define NBLK 256

typedef __attribute__((ext_vector_type(8))) short bf16x8;
typedef __attribute__((ext_vector_type(4))) float f32x4;
typedef __attribute__((ext_vector_type(4))) unsigned int u32x4;
typedef __attribute__((ext_vector_type(2))) unsigned int u32x2;

__device__ __forceinline__ ushort f2bf(float v) {
    union { float f; uint32_t u; } x; x.f = v;
    uint32_t r = x.u + 0x7fff + ((x.u >> 16) & 1);
    return (ushort)(r >> 16);
}

__device__ __forceinline__ float sigf(float x) {   // 1/(1+e^-x), saturation-safe
    return 1.f / (1.f + __expf(-x));
}

// Fragment-major layout for [64][1024] bf16 activation slabs:
//   off(b,u) = (b>>4)*16384 + (u>>5)*512 + ((u>>3)&3)*128 + (b&15)*8 + (u&7)
// A wave loading m-tile r, k-tile kt reads 64 lanes x 16B CONTIGUOUS 1KB.

// Build Wt[l][col'][k] bf16, col' = u*4+g for source column col=g*1024+u.
// Stores use sc0 sc1 (write-through, no L2 residue): the Wt region is later
// REUSED as the layer-1 h ring, read with plain cached loads.
__global__ __launch_bounds__(256) void k_prep_wt(const float* __restrict__ wih,
                                                 const float* __restrict__ whh,
                                                 ushort* __restrict__ Wt) {
    __shared__ ushort tile[64][65];
    const int l = blockIdx.z;
    const int k0 = blockIdx.x * 64;    // 0..2047
    const int col0 = blockIdx.y * 64;  // 0..4095
    const int tid = threadIdx.x;
    const int cl = tid & 63, ks = tid >> 6;
    const float* src;
    int krow0;
    if (k0 < 1024) { src = wih + (size_t)l * 1024 * 4096; krow0 = k0; }
    else           { src = whh + (size_t)l * 1024 * 4096; krow0 = k0 - 1024; }
#pragma unroll
    for (int i = 0; i < 16; ++i) {
        int kl = ks + i * 4;
        tile[kl][cl] = f2bf(src[(size_t)(krow0 + kl) * 4096 + col0 + cl]);
    }
    __syncthreads();
    const int g0 = col0 >> 10, ub = col0 & 1023;
    ushort* dst = Wt + (size_t)l * 4096 * 2048;
    const int klane = tid & 63;
#pragma unroll
    for (int i = 0; i < 16; ++i) {
        int cl2 = (tid >> 6) + i * 4;
        int row = (ub + cl2) * 4 + g0;
        ushort* p = dst + (size_t)row * 2048 + k0 + klane;
        uint v = (uint)tile[klane][cl2];
        asm volatile("global_store_short %0, %1, off sc0 sc1"
                     :: "v"(p), "v"(v) : "memory");
    }
}

// x -> bf16 fragment-major xbfF[t][...]
__global__ __launch_bounds__(256) void k_cast_x(const float* __restrict__ x,
                                                ushort* __restrict__ xbfF) {
    int i = blockIdx.x * 256 + threadIdx.x;   // [256 t][64 b][128 k8]
    int k8 = i & 127, b = (i >> 7) & 63, t = i >> 13;
    const float4* xs = (const float4*)(x + (((size_t)t * 64 + b) * 1024 + k8 * 8));
    float4 a = xs[0], c = xs[1];
    uint4 pk;
    pk.x = (uint)f2bf(a.x) | ((uint)f2bf(a.y) << 16);
    pk.y = (uint)f2bf(a.z) | ((uint)f2bf(a.w) << 16);
    pk.z = (uint)f2bf(c.x) | ((uint)f2bf(c.y) << 16);
    pk.w = (uint)f2bf(c.z) | ((uint)f2bf(c.w) << 16);
    size_t off = (size_t)t * 65536 + (size_t)(b >> 4) * 16384 +
                 (size_t)(k8 >> 2) * 512 + (size_t)(k8 & 3) * 128 + (size_t)(b & 15) * 8;
    *(uint4*)(xbfF + off) = pk;
}

// const[l][b][col] = a0[b,:] @ W_ah[l][:,col] + bias_ah + bias_ih + bias_hh
__global__ __launch_bounds__(256) void k_const(const float* __restrict__ attn,
                                               const float* __restrict__ wah,
                                               const float* __restrict__ bah,
                                               const float* __restrict__ bih,
                                               const float* __restrict__ bhh,
                                               float* __restrict__ constg) {
    const int tid = threadIdx.x;
    const int col = blockIdx.x * 256 + tid;
    const int b0 = blockIdx.y * 8;
    const int l = blockIdx.z;
    const float* W = wah + (size_t)l * 512 * 4096;
    float acc[8] = {0.f, 0.f, 0.f, 0.f, 0.f, 0.f, 0.f, 0.f};
    for (int k = 0; k < 512; ++k) {
        float wv = W[(size_t)k * 4096 + col];
#pragma unroll
        for (int j = 0; j < 8; ++j) acc[j] += attn[(b0 + j) * 512 + k] * wv;
    }
    float bias = bah[l * 4096 + col] + bih[l * 4096 + col] + bhh[l * 4096 + col];
    float* cg = constg + (size_t)l * B4H;
#pragma unroll
    for (int j = 0; j < 8; ++j) cg[(size_t)(b0 + j) * 4096 + col] = acc[j] + bias;
}

// h0 -> fragment-major initial slots
__global__ __launch_bounds__(256) void k_init(const float* __restrict__ h0,
                                              ushort* __restrict__ hs0F,
                                              ushort* __restrict__ h1s0,
                                              unsigned* __restrict__ flags) {
    int i = blockIdx.x * 256 + threadIdx.x;   // [2 l][64 b][128 k8] = 16384
    if (i < 16384) {
        int k8 = i & 127, b = (i >> 7) & 63, l = i >> 13;
        const float* src = h0 + ((size_t)(l * 64 + b) * 1024 + k8 * 8);
        uint4 pk;
        pk.x = (uint)f2bf(src[0]) | ((uint)f2bf(src[1]) << 16);
        pk.y = (uint)f2bf(src[2]) | ((uint)f2bf(src[3]) << 16);
        pk.z = (uint)f2bf(src[4]) | ((uint)f2bf(src[5]) << 16);
        pk.w = (uint)f2bf(src[6]) | ((uint)f2bf(src[7]) << 16);
        size_t off = (size_t)(b >> 4) * 16384 + (size_t)(k8 >> 2) * 512 +
                     (size_t)(k8 & 3) * 128 + (size_t)(b & 15) * 8;
        *(uint4*)((l == 0 ? hs0F : h1s0) + off) = pk;
    }
    if (i < NBLK) flags[i] = 0u;
}

// ---- inline-asm helpers ----
// Issue one chunk of 8 x 16B fragment loads (contiguous 1KB per instr).
#define ISSUE(BUF, BASE)                                                       \
    do {                                                                       \
        _Pragma("unroll")                                                      \
        for (int _i = 0; _i < 8; ++_i)                                         \
            asm volatile("global_load_dwordx4 %0, %1, off"                     \
                         : "=v"(BUF[_i]) : "v"((BASE) + _i * 512));            \
    } while (0)

#define CONSUME(BUF, c, N)                                                     \
    do {                                                                       \
        asm volatile("s_waitcnt vmcnt(" #N ")" ::: "memory");                  \
        __builtin_amdgcn_sched_barrier(0x100);                                 \
        _Pragma("unroll")                                                      \
        for (int _i = 0; _i < 8; ++_i) {                                       \
            bf16x8 b = *(const bf16x8*)(bbase + ((c) * 8 + _i) * 512);         \
            acc = __builtin_amdgcn_mfma_f32_16x16x32_bf16(BUF[_i], b, acc, 0, 0, 0); \
        }                                                                      \
    } while (0)

// Persistent pipelined 2-layer LSTM. 256 blocks x 512 threads, 1 block/CU.
// Wt doubles as the layer-1 h ring (slots 1..256) after prologue staging:
// - Wt was written by k_prep_wt with sc stores (no L2 residue),
// - staged into LDS here with sc loads (no L2 allocation),
// - slot s is first written at iter s>=1, AFTER the barrier proving all
//   blocks finished staging (flag>=1 implies prologue done).
__global__ __launch_bounds__(512, 1) void k_persist(
        const ushort* __restrict__ xbfF,
        ushort* __restrict__ hs0F,
        const ushort* __restrict__ h1s0,
        ushort* Wt,                       // staging source + h1 ring (aliased)
        const float* __restrict__ constg,
        const float* __restrict__ c0,
        float* __restrict__ out,
        unsigned* __restrict__ flags) {
    __shared__ ushort wlds[65536];   // [2 l][256 kg][16 col][8 k] = 128 KiB
    __shared__ float gt[8][16][17];

    const int tid = threadIdx.x;
    const int w = tid >> 6, lane = tid & 63;
    const int layer = w >> 2, wm = w & 3;
    const int u0 = blockIdx.x * 4;
    const int bid = blockIdx.x;

    // ---- stage weights into LDS (once), via sc loads (bypass L2) ----
    {
        bf16x8 vst[16];
#pragma unroll
        for (int i = 0; i < 16; ++i) {
            int c = i * 512 + tid;
            int ly = c >> 12, r = c & 4095;
            int col = r >> 8, kg = r & 255;
            const ushort* src = Wt + ((size_t)(ly * 4096 + u0 * 4 + col)) * 2048 + kg * 8;
            asm volatile("global_load_dwordx4 %0, %1, off sc0 sc1"
                         : "=v"(vst[i]) : "v"(src));
        }
        asm volatile("s_waitcnt vmcnt(0)" ::: "memory");
        __builtin_amdgcn_sched_barrier(0);
#pragma unroll
        for (int i = 0; i < 16; ++i) {
            int c = i * 512 + tid;
            int ly = c >> 12, r = c & 4095;
            int col = r >> 8, kg = r & 255;
            int slot = ly * 4096 + kg * 16 + col;
            *(bf16x8*)(wlds + (size_t)slot * 8) = vst[i];
        }
    }

    // ---- launch-invariant per-thread state ----
    // MFMA C/D mapping: col = lane&15, row = (lane>>4)*4 + r
    const int cc = lane & 15;
    const int gu = u0 + (cc >> 2), gg_ = cc & 3, gcol = (gg_ << 10) + gu;
    const int r0 = (lane >> 4) * 4;
    const float* cgp = constg + (size_t)layer * B4H;
    float cg[4];
#pragma unroll
    for (int r = 0; r < 4; ++r)
        cg[r] = cgp[(size_t)(wm * 16 + r0 + r) * 4096 + gcol];

    const int bl = lane & 15, ul = lane >> 4;
    const int eidx = (wm * 16 + bl) * 1024 + (u0 + ul);
    float creg = c0[layer * BH + eidx];

    // fragment-major read base offset for this lane (ushorts)
    const size_t fro = (size_t)wm * 16384 + (size_t)lane * 8;
    // packed h-store offset (ushorts), lanes 0-15 store dwordx2
    const int hoff = wm * 16384 + ((u0 >> 5) << 9) + (((u0 >> 3) & 3) << 7) +
                     (bl << 3) + (u0 & 4);
    const ushort* bbase = wlds + ((size_t)layer * 4096 + lane) * 8;

    __syncthreads();

    for (int s = 0; s <= TT; ++s) {
        const int act0 = (layer == 0) && (s < TT);
        const int act1 = (layer == 1) && (s >= 1);
        const int t1 = s - 1;

        bf16x8 bufA[8], bufB[8], bufC[8], bufD[8];

        // (A) prefetch layer0 x-chunks (static input, no barrier dependency)
        //     and COMPLETE them before the poll: landed registers are safe to
        //     copy/spill; in-flight asm destinations are NOT.
        if (act0) {
            const ushort* Axl = xbfF + (size_t)s * 65536 + fro;
            ISSUE(bufA, Axl + 0 * 4096);
            ISSUE(bufB, Axl + 1 * 4096);
            ISSUE(bufC, Axl + 2 * 4096);
            ISSUE(bufD, Axl + 3 * 4096);
            asm volatile("s_waitcnt vmcnt(0)" ::: "memory");
            __builtin_amdgcn_sched_barrier(0);
        }

        // (B) grid barrier wait: all blocks finished iter s-1.
        if (s > 0) {
            if (w == 0) {
                const unsigned target = (unsigned)s;
                const unsigned* fp = flags + lane * 4;
                while (true) {
                    u32x4 f;
                    asm volatile("global_load_dwordx4 %0, %1, off sc0 sc1\n\t"
                                 "s_waitcnt vmcnt(0)"
                                 : "=v"(f) : "v"(fp) : "memory");
                    int ok = (f.x >= target) && (f.y >= target) &&
                             (f.z >= target) && (f.w >= target);
                    if (__all(ok)) break;
                    __builtin_amdgcn_s_sleep(2);
                }
            }
            __syncthreads();
        }

        // (C) compute
        float hv = 0.f, cn = 0.f;
        if (act0 | act1) {
            f32x4 acc = {0.f, 0.f, 0.f, 0.f};
            const ushort* Ahl;
            if (layer == 0) {
                Ahl = hs0F + (size_t)s * 65536 + fro;
            } else {
                const ushort* Axl = hs0F + (size_t)s * 65536 + fro;
                Ahl = (t1 == 0 ? h1s0 : (const ushort*)Wt + (size_t)(t1 - 1) * 65536) + fro;
                ISSUE(bufA, Axl + 0 * 4096);
                ISSUE(bufB, Axl + 1 * 4096);
                ISSUE(bufC, Axl + 2 * 4096);
                ISSUE(bufD, Axl + 3 * 4096);
            }
            CONSUME(bufA, 0, 24); ISSUE(bufA, Ahl + 0 * 4096);
            CONSUME(bufB, 1, 24); ISSUE(bufB, Ahl + 1 * 4096);
            CONSUME(bufC, 2, 24); ISSUE(bufC, Ahl + 2 * 4096);
            CONSUME(bufD, 3, 24); ISSUE(bufD, Ahl + 3 * 4096);
            CONSUME(bufA, 4, 24);
            CONSUME(bufB, 5, 16);
            CONSUME(bufC, 6, 8);
            CONSUME(bufD, 7, 0);
#pragma unroll
            for (int r = 0; r < 4; ++r)
                gt[w][r0 + r][cc] = acc[r] + cg[r];
            __builtin_amdgcn_wave_barrier();
            asm volatile("s_waitcnt lgkmcnt(0)" ::: "memory");
            float gi = gt[w][bl][ul * 4 + 0];
            float gf = gt[w][bl][ul * 4 + 1];
            float gv = gt[w][bl][ul * 4 + 2];
            float go = gt[w][bl][ul * 4 + 3];
            float si = sigf(gi), sf = sigf(gf), so = sigf(go);
            cn = sf * creg + si * (2.f * sigf(2.f * gv) - 1.f);
            hv = so * (2.f * sigf(2.f * cn) - 1.f);
            creg = cn;
            uint hb = (uint)f2bf(hv);
            // pack 4 u-values per batch row via intra-wave shuffles
            uint g0 = __shfl(hb, bl);
            uint g1 = __shfl(hb, bl + 16);
            uint g2 = __shfl(hb, bl + 32);
            uint g3 = __shfl(hb, bl + 48);
            u32x2 hp;
            hp.x = (g0 & 0xffffu) | (g1 << 16);
            hp.y = (g2 & 0xffffu) | (g3 << 16);
            ushort* hdst = (layer == 0 ? hs0F + (size_t)(s + 1) * 65536
                                       : Wt + (size_t)t1 * 65536) + hoff;
            if (lane < 16)
                asm volatile("global_store_dwordx2 %0, %1, off sc0 sc1"
                             :: "v"(hdst), "v"(hp) : "memory");
        }

        // (D) drain h-stores, signal
        if (s < TT) {
            asm volatile("s_waitcnt vmcnt(0)" ::: "memory");
            __syncthreads();
            if (tid == 0) {
                unsigned tgt = (unsigned)(s + 1);
                unsigned* fp = flags + bid;
                asm volatile("global_store_dword %0, %1, off sc0 sc1"
                             :: "v"(fp), "v"(tgt) : "memory");
            }
        }

        // (E) out-stores (kernel-exit data only; overlap next iter's poll)
        if (act1) {
            float4 ov;
            ov.x = __shfl(hv, bl);
            ov.y = __shfl(hv, bl + 16);
            ov.z = __shfl(hv, bl + 32);
            ov.w = __shfl(hv, bl + 48);
            if (lane < 16)
                *(float4*)(out + (size_t)t1 * 65536 + (wm * 16 + bl) * 1024 + u0) = ov;
            if (t1 == TT - 1) {
                out[OUT_HL + BH + eidx] = hv;
                out[OUT_CL + BH + eidx] = cn;
            }
        } else if (act0 && s == TT - 1) {
            out[OUT_HL + eidx] = hv;
            out[OUT_CL + eidx] = cn;
        }
    }
}

extern "C" void kernel_launch(void* const* d_in, const int* in_sizes, int n_in,
                              void* d_out, int out_size, void* d_ws, size_t ws_size,
                              hipStream_t stream) {
    const float* attn = (const float*)d_in[0];
    const float* x    = (const float*)d_in[1];
    const float* h0   = (const float*)d_in[3];
    const float* c0   = (const float*)d_in[4];
    const float* wah  = (const float*)d_in[5];
    const float* wih  = (const float*)d_in[6];
    const float* whh  = (const float*)d_in[7];
    const float* bah  = (const float*)d_in[8];
    const float* bih  = (const float*)d_in[9];
    const float* bhh  = (const float*)d_in[10];
    float* out = (float*)d_out;

    char* ws = (char*)d_ws;
    ushort*   Wt     = (ushort*)(ws);               // [2][4096][2048] bf16 : 33,554,432
                                                    //   (reused as h1 ring slots 1..256)
    ushort*   xbfF   = (ushort*)(ws + 33554432);    // frag-major x     : 33,554,432
    ushort*   hs0F   = (ushort*)(ws + 67108864);    // [257] slots      : 33,685,504
    ushort*   h1s0   = (ushort*)(ws + 100794368);   // h1 ring slot 0   : 131,072
    float*    constg = (float*)(ws + 100925440);    // [2][64][4096]    : 2,097,152
    unsigned* flags  = (unsigned*)(ws + 103022592); // [256] u32
    // total 103,023,616 B  (< round-4's proven 103.7 MB footprint)

    hipLaunchKernelGGL(k_prep_wt, dim3(32, 64, 2), dim3(256), 0, stream, wih, whh, Wt);
    hipLaunchKernelGGL(k_cast_x, dim3(8192), dim3(256), 0, stream, x, xbfF);
    hipLaunchKernelGGL(k_const, dim3(16, 8, 2), dim3(256), 0, stream, attn, wah, bah, bih, bhh, constg);
    hipLaunchKernelGGL(k_init, dim3(64), dim3(256), 0, stream, h0, hs0F, h1s0, flags);

    void* args[] = { (void*)&xbfF, (void*)&hs0F, (void*)&h1s0, (void*)&Wt,
                     (void*)&constg, (void*)&c0, (void*)&out, (void*)&flags };
    hipLaunchCooperativeKernel((void*)k_persist, dim3(NBLK), dim3(512), args, 0, stream);
}